// Round 3
// baseline (394.250 us; speedup 1.0000x reference)
//
#include <hip/hip_runtime.h>

// Problem constants (from reference setup_inputs)
constexpr int B = 32, P = 3, C = 512, N = 1024;
constexpr int G = B * P;             // 96 (b,p) groups

// ws need for a given C-split: CSPLIT * G * N * float2
constexpr size_t ws_need(int csplit) {
    return (size_t)csplit * G * N * 2 * sizeof(float);
}

// ---- Kernel 1: partial L1/L2 over a C-chunk, explicit 2-stage software
// pipeline: the next 4-row group's 8 float4 loads are issued BEFORE the
// current group is consumed, so ~16 loads (16 KB/wave) stay in flight.
// __launch_bounds__(256,4) allows up to 128 VGPRs (16 waves/CU) so the
// pipeline registers are not squeezed out (previous version: 36 VGPRs ->
// compiler drained vmcnt to ~0 between tiny load clusters -> 4.9 B/cy/CU).
template <int CSPLIT>
__global__ __launch_bounds__(256, 4) void dist_partial(
    const float* __restrict__ x1, const float* __restrict__ x2,
    float* __restrict__ ws)
{
    constexpr int CCHUNK = C / CSPLIT;   // rows of C per block
    constexpr int R = 4;                 // rows per pipeline stage
    constexpr int NJ = CCHUNK / R;       // pipeline stages
    static_assert(CCHUNK % R == 0, "chunk must be multiple of stage rows");

    const int g     = blockIdx.x / CSPLIT;
    const int chunk = blockIdx.x % CSPLIT;
    const int t     = threadIdx.x;       // owns n = 4t..4t+3

    const float4* pa = (const float4*)(x1 + (size_t)g * C * N)
                       + (size_t)chunk * CCHUNK * (N / 4) + t;
    const float4* pb = (const float4*)(x2 + (size_t)g * C * N)
                       + (size_t)chunk * CCHUNK * (N / 4) + t;

    float4 l1 = make_float4(0.f, 0.f, 0.f, 0.f);
    float4 l2 = make_float4(0.f, 0.f, 0.f, 0.f);

    // All indices compile-time (full unroll) so these arrays live in VGPRs.
    float4 ca[R], cb[R], na[R], nb[R];

    #pragma unroll
    for (int r = 0; r < R; ++r) {
        ca[r] = pa[r * (N / 4)];
        cb[r] = pb[r * (N / 4)];
    }
    pa += R * (N / 4);
    pb += R * (N / 4);

    #pragma unroll
    for (int j = 0; j < NJ; ++j) {
        // Stage j+1 loads issued before stage j is consumed (compile-time
        // branch; fully unrolled). Keeps vmcnt high across the VALU body.
        if (j + 1 < NJ) {
            #pragma unroll
            for (int r = 0; r < R; ++r) {
                na[r] = pa[r * (N / 4)];
                nb[r] = pb[r * (N / 4)];
            }
            pa += R * (N / 4);
            pb += R * (N / 4);
        }

        #pragma unroll
        for (int r = 0; r < R; ++r) {
            float d;
            d = ca[r].x - cb[r].x; l1.x += fabsf(d); l2.x = fmaf(d, d, l2.x);
            d = ca[r].y - cb[r].y; l1.y += fabsf(d); l2.y = fmaf(d, d, l2.y);
            d = ca[r].z - cb[r].z; l1.z += fabsf(d); l2.z = fmaf(d, d, l2.z);
            d = ca[r].w - cb[r].w; l1.w += fabsf(d); l2.w = fmaf(d, d, l2.w);
        }

        if (j + 1 < NJ) {
            #pragma unroll
            for (int r = 0; r < R; ++r) {
                ca[r] = na[r];
                cb[r] = nb[r];
            }
        }
    }

    // ws layout: float2 ws2[(chunk*G + g)*N + n] = (l1, l2). Thread writes
    // 4 consecutive float2 = 32 B -> two float4 stores, wave-contiguous 2 KB.
    float4* wout = (float4*)ws + ((size_t)(chunk * G + g) * N) / 2 + 2 * t;
    wout[0] = make_float4(l1.x, l2.x, l1.y, l2.y);
    wout[1] = make_float4(l1.z, l2.z, l1.w, l2.w);
}

// ---- Kernel 2: combine CSPLIT partials per (g,n), emit [l1, sq_l2, l1].
template <int CSPLIT>
__global__ __launch_bounds__(256) void dist_combine(
    const float* __restrict__ ws, float* __restrict__ out)
{
    const int idx = blockIdx.x * 256 + threadIdx.x;   // (g,n) flat, 0..98303
    const float2* ws2 = (const float2*)ws;
    float l1 = 0.f, l2 = 0.f;
    #pragma unroll
    for (int chunk = 0; chunk < CSPLIT; ++chunk) {
        const float2 v = ws2[(size_t)chunk * G * N + idx];
        l1 += v.x;
        l2 += v.y;
    }
    out[3 * (size_t)idx + 0] = l1;
    out[3 * (size_t)idx + 1] = l2;
    out[3 * (size_t)idx + 2] = l1;
}

// ---- Fallback (ws too small): original atomic path, correctness-safe.
constexpr int FB_CSPLIT = 16;
constexpr int FB_CCHUNK = C / FB_CSPLIT;
__global__ __launch_bounds__(256) void dist_atomic(
    const float* __restrict__ x1, const float* __restrict__ x2,
    float* __restrict__ out)
{
    const int g     = blockIdx.x / FB_CSPLIT;
    const int chunk = blockIdx.x % FB_CSPLIT;
    const int t     = threadIdx.x;
    const float4* a = (const float4*)(x1 + (size_t)g * C * N) + t;
    const float4* b = (const float4*)(x2 + (size_t)g * C * N) + t;
    const int c0 = chunk * FB_CCHUNK;
    float4 l1 = make_float4(0.f, 0.f, 0.f, 0.f);
    float4 l2 = make_float4(0.f, 0.f, 0.f, 0.f);
    for (int c = c0; c < c0 + FB_CCHUNK; ++c) {
        const float4 av = a[(size_t)c * (N / 4)];
        const float4 bv = b[(size_t)c * (N / 4)];
        float d;
        d = av.x - bv.x; l1.x += fabsf(d); l2.x = fmaf(d, d, l2.x);
        d = av.y - bv.y; l1.y += fabsf(d); l2.y = fmaf(d, d, l2.y);
        d = av.z - bv.z; l1.z += fabsf(d); l2.z = fmaf(d, d, l2.z);
        d = av.w - bv.w; l1.w += fabsf(d); l2.w = fmaf(d, d, l2.w);
    }
    const size_t obase = ((size_t)g * N + 4 * (size_t)t) * 3;
    const float l1v[4] = {l1.x, l1.y, l1.z, l1.w};
    const float l2v[4] = {l2.x, l2.y, l2.z, l2.w};
    #pragma unroll
    for (int i = 0; i < 4; ++i) {
        atomicAdd(&out[obase + 3 * i + 0], l1v[i]);
        atomicAdd(&out[obase + 3 * i + 1], l2v[i]);
        atomicAdd(&out[obase + 3 * i + 2], l1v[i]);
    }
}

extern "C" void kernel_launch(void* const* d_in, const int* in_sizes, int n_in,
                              void* d_out, int out_size, void* d_ws, size_t ws_size,
                              hipStream_t stream) {
    const float* x1 = (const float*)d_in[0];
    const float* x2 = (const float*)d_in[1];
    float* out = (float*)d_out;

    if (ws_size >= ws_need(32)) {
        // 3072 blocks = 12/CU: exactly 3 occupancy rounds at the 16-wave
        // (4-block) residency cap -> no tail imbalance.
        dist_partial<32><<<G * 32, 256, 0, stream>>>(x1, x2, (float*)d_ws);
        dist_combine<32><<<(G * N) / 256, 256, 0, stream>>>((const float*)d_ws, out);
    } else if (ws_size >= ws_need(16)) {
        dist_partial<16><<<G * 16, 256, 0, stream>>>(x1, x2, (float*)d_ws);
        dist_combine<16><<<(G * N) / 256, 256, 0, stream>>>((const float*)d_ws, out);
    } else {
        hipMemsetAsync(d_out, 0, (size_t)out_size * sizeof(float), stream);
        dist_atomic<<<G * FB_CSPLIT, 256, 0, stream>>>(x1, x2, out);
    }
}